// Round 15
// baseline (1293.613 us; speedup 1.0000x reference)
//
#include <hip/hip_runtime.h>
#include <stdint.h>

// ---- problem constants ----
#define NBG   64      // graphs
#define NPER  32      // nodes per graph
#define DNODE 320
#define FEAT  1472
#define HIDN  2944
#define FEATP 1536    // FEAT padded to x128 for layer-2 N
#define NA    11
#define NROWS 2048    // NBG*NPER
#define MEDGE 65536   // NBG*NPER*NPER

typedef __attribute__((ext_vector_type(8))) short    bf16x8;
typedef __attribute__((ext_vector_type(4))) float    fv4;
typedef __attribute__((ext_vector_type(2))) float    fv2;
typedef __attribute__((ext_vector_type(16))) float   fv16;
typedef __attribute__((ext_vector_type(4))) unsigned uiv4;

__device__ __forceinline__ unsigned short f2bf(float f) {
  unsigned u = __builtin_bit_cast(unsigned, f);
  u += 0x7fffu + ((u >> 16) & 1u);
  return (unsigned short)(u >> 16);
}
__device__ __forceinline__ float bf2f(unsigned short h) {
  unsigned u = ((unsigned)h) << 16;
  return __builtin_bit_cast(float, u);
}
__device__ __forceinline__ unsigned cvt_pk_bf16(float lo, float hi) {
  unsigned r;
  asm("v_cvt_pk_bf16_f32 %0, %1, %2" : "=v"(r) : "v"(lo), "v"(hi));
  return r;
}
// packed f32 add (VOP3P) — one instr for two adds
__device__ __forceinline__ fv2 pk_add(fv2 a, fv2 b) {
  fv2 d;
  asm("v_pk_add_f32 %0, %1, %2" : "=v"(d) : "v"(a), "v"(b));
  return d;
}
// relu on 2 packed bf16: positive bf16 sorts as positive i16; negative -> 0.
__device__ __forceinline__ unsigned pk_relu2(unsigned x, unsigned z) {
  unsigned r;
  asm("v_pk_max_i16 %0, %1, %2" : "=v"(r) : "v"(x), "v"(z));
  return r;
}
__device__ __forceinline__ fv2 lo2(fv4 v) { return __builtin_shufflevector(v, v, 0, 1); }
__device__ __forceinline__ fv2 hi2(fv4 v) { return __builtin_shufflevector(v, v, 2, 3); }
// async global->LDS, 16B per lane; lds base wave-uniform (HW adds lane*16)
__device__ __forceinline__ void gload_lds16(const void* g, void* l) {
  __builtin_amdgcn_global_load_lds((const __attribute__((address_space(1))) void*)g,
                                   (__attribute__((address_space(3))) void*)l, 16, 0, 0);
}

// ---- transpose f32 [K][N] -> bf16 [Npad][K]; rows n>=N zero-filled ----
__global__ void k_transpose_bf16(const float* __restrict__ src, unsigned short* __restrict__ dst,
                                 int K, int N, int Npad) {
  __shared__ float tile[64][65];
  int k0 = blockIdx.x * 64, n0 = blockIdx.y * 64;
  int r = threadIdx.x >> 2, cb = (threadIdx.x & 3) * 16;
  const float* srow = src + (size_t)(k0 + r) * N + n0 + cb;
#pragma unroll
  for (int c = 0; c < 16; ++c) {
    int n = n0 + cb + c;
    tile[r][cb + c] = (n < N) ? srow[c] : 0.f;
  }
  __syncthreads();
  unsigned short* drow = dst + (size_t)(n0 + r) * K + k0 + cb;
#pragma unroll
  for (int c = 0; c < 16; ++c) drow[c] = f2bf(tile[cb + c][r]);
}

// ---- embeddings -> xb bf16 [2048][320] ----
__global__ void k_embed(const int* __restrict__ idx, const int* __restrict__ mlt,
                        const float* __restrict__ id_emb, const float* __restrict__ mult_emb,
                        unsigned short* __restrict__ xb) {
  int t = blockIdx.x, c = threadIdx.x;
  int iv = idx[t], mv = mlt[t];
  xb[t * DNODE + c] = f2bf(id_emb[iv * 256 + c]);
  if (c < 64) xb[t * DNODE + 256 + c] = f2bf(mult_emb[mv * 64 + c]);
}

// ---- agg f32 [64][320] = mean over 32 nodes ----
__global__ void k_agg(const unsigned short* __restrict__ xb, float* __restrict__ agg) {
  int b = blockIdx.x;
  for (int d = threadIdx.x; d < DNODE; d += 256) {
    float s = 0.f;
    for (int i = 0; i < NPER; ++i) s += bf2f(xb[(b * NPER + i) * DNODE + d]);
    agg[b * DNODE + d] = s * (1.f / 32.f);
  }
}

// ---- za bf16 [128][832] = [z | agg], rows 64..127 zero ----
__global__ void k_za(const float* __restrict__ z, const float* __restrict__ agg,
                     unsigned short* __restrict__ za) {
  int b = blockIdx.x;
  for (int c = threadIdx.x; c < 832; c += 256) {
    unsigned short v = 0;
    if (b < NBG) v = (c < 512) ? f2bf(z[b * 512 + c]) : f2bf(agg[b * DNODE + (c - 512)]);
    za[b * 832 + c] = v;
  }
}

// ---- layer-1 GEMM: C[M][2944] (f32) = A(bf16,[M][sA] slice) @ W1T(bf16 [2944][1472])^T ----
__global__ void k_gemm1(const unsigned short* __restrict__ A, int sA, int Mrows,
                        const unsigned short* __restrict__ W1T, int kOff, int Ksteps,
                        float* __restrict__ C, const float* __restrict__ bias) {
  __shared__ alignas(16) unsigned short Als[128 * 32];
  __shared__ alignas(16) unsigned short Bls[128 * 32];
  int bx = blockIdx.x;
  int mt = bx / 23, nc = bx - mt * 23;
  int m0 = mt * 128, n0 = nc * 128;
  int tid = threadIdx.x, lane = tid & 63, w = tid >> 6;

  fv4 acc[4][4] = {};
  for (int kt = 0; kt < Ksteps; ++kt) {
    int k0 = kt * 32;
    __syncthreads();
#pragma unroll
    for (int q = 0; q < 2; ++q) {
      int seg = w * 2 + q;
      int row = seg * 16 + (lane >> 2);
      int col = (lane & 3) * 8;
      gload_lds16(A + (size_t)(m0 + row) * sA + k0 + col, &Als[seg * 512]);
      gload_lds16(W1T + (size_t)(n0 + row) * FEAT + kOff + k0 + col, &Bls[seg * 512]);
    }
    __syncthreads();
    bf16x8 aF[4], bF[4];
#pragma unroll
    for (int mf = 0; mf < 4; ++mf)
      aF[mf] = *(const bf16x8*)&Als[((w >> 1) * 64 + mf * 16 + (lane & 15)) * 32 + (lane >> 4) * 8];
#pragma unroll
    for (int nf = 0; nf < 4; ++nf)
      bF[nf] = *(const bf16x8*)&Bls[((w & 1) * 64 + nf * 16 + (lane & 15)) * 32 + (lane >> 4) * 8];
#pragma unroll
    for (int mf = 0; mf < 4; ++mf)
#pragma unroll
      for (int nf = 0; nf < 4; ++nf)
        acc[mf][nf] = __builtin_amdgcn_mfma_f32_16x16x32_bf16(aF[mf], bF[nf], acc[mf][nf], 0, 0, 0);
  }
  int mq = (w >> 1) * 64, nq = (w & 1) * 64;
#pragma unroll
  for (int mf = 0; mf < 4; ++mf)
#pragma unroll
    for (int nf = 0; nf < 4; ++nf) {
      int n = n0 + nq + nf * 16 + (lane & 15);
      float bv = bias ? bias[n] : 0.f;
#pragma unroll
      for (int r = 0; r < 4; ++r) {
        int m = m0 + mq + mf * 16 + (lane >> 4) * 4 + r;
        if (m < Mrows) C[(size_t)m * HIDN + n] = acc[mf][nf][r] + bv;
      }
    }
}

// ---- PQ1 = P1 + Q[b] (in place on P1; Q already includes b1) ----
__global__ void k_pq(float* __restrict__ P1, const float* __restrict__ Q) {
  int r = blockIdx.x;
  const float* q = Q + (size_t)(r >> 5) * HIDN;
  float* p = P1 + (size_t)r * HIDN;
  for (int n = threadIdx.x; n < HIDN; n += 256) p[n] += q[n];
}

__global__ void k_zero(float* __restrict__ p, int n) {
  int i = blockIdx.x * 256 + threadIdx.x;
  if (i < n) p[i] = 0.f;
}

// ---- layer-2 GEMM fused with layer-3 partial, N=256, 32x32x16 MFMA ----
// R11 champion structure (3072 blocks, nc-major XCD order, 2-barrier
// double-buffered staging, packed-math A-construct, atomic epilogue) with the
// MFMA shape switched to v_mfma_f32_32x32x16_bf16: wave tile 64m x 128n as
// 2x4 fragments of 32x32, acc[2][4] f32x16 (128 regs, same as before), but
// 16 MFMA per K=32 step instead of 32 (half the instruction count, higher
// FLOP/cyc ceiling). Operand layouts (verified-by-analogy to the 16x16 maps):
//   A: row(j)=lane&31, k=(lane>>5)*8+e  -> P2[lane&31] + broadcast Q[i_mf]
//   B: col(n)=lane&31, k=(lane>>5)*8+e  -> W2T row nf*32+(lane&31)
//   C/D: col=lane&31, row=(reg&3)+8*(reg>>2)+4*(lane>>5)
// P2 LDS uses a finer 16B-slot XOR swizzle (slot ^ (j&7)) -> 4-way conflicts.
// LDS: B[2][16384] @0 | P2s[2][4096] @32768 | PQ1s[2][1024] @40960 = 43008
__global__ __launch_bounds__(256, 2)
void k_gemm2(const float* __restrict__ PQ1, const float* __restrict__ P2,
             const unsigned short* __restrict__ W2T,
             const float* __restrict__ b2, const float* __restrict__ W3,
             float* __restrict__ Lout) {
  __shared__ alignas(16) unsigned char LB[43008];
  int raw = blockIdx.x;
  int g = (raw & 7) * 384 + (raw >> 3);   // bijective: 3072 = 8 * 384
  int nc2 = g / 512;                      // panel index (nc-major per XCD)
  int mt  = g - nc2 * 512;
  int m0 = mt * 128, n0 = nc2 * 256;
  int tid = threadIdx.x, lane = tid & 63, w = tid >> 6;
  int bG = m0 >> 10;             // graph index
  int i0 = (m0 >> 5) & 31;       // first of the 4 i-rows of this m-tile
  int mw = w >> 1;               // m-half (64 rows)
  int nw = w & 1;                // n-half (128 cols)
  int jj = lane & 31;            // A-row (j) / B-col within fragment
  int lh = lane >> 5;            // k-subslice selector

  const int swcolB = ((lane & 3) ^ ((lane >> 3) & 3)) * 8;         // B source swizzle (bf16 elems)
  const int swcolP = ((lane & 7) ^ ((lane >> 3) & 7)) * 4;         // P2 source swizzle (f32, 16B slots)

  auto STAGEB = [&](int kt, int buf) {
#pragma unroll
    for (int q = 0; q < 4; ++q) {
      int seg = w * 4 + q;
      int row = seg * 16 + (lane >> 2);
      gload_lds16(W2T + (size_t)(n0 + row) * HIDN + kt * 32 + swcolB,
                  LB + buf * 16384 + seg * 1024);
    }
  };
  auto STAGESRC = [&](int kt, int buf) {
    gload_lds16(P2 + (size_t)(bG * NPER + 8 * w + (lane >> 3)) * HIDN + kt * 32 + swcolP,
                LB + 32768 + buf * 4096 + w * 1024);
    if (w == 0)
      gload_lds16(PQ1 + (size_t)(bG * NPER + i0 + (lane >> 3)) * HIDN + kt * 32 + (lane & 7) * 4,
                  LB + 40960 + buf * 1024);
  };

  fv16 acc[2][4] = {};
  unsigned z0 = 0;
  asm volatile("" : "+v"(z0));   // keep zero in a VGPR for pk_max

  STAGEB(0, 0);
  STAGESRC(0, 0);
  __syncthreads();

  for (int kt = 0; kt < 92; ++kt) {
    int cur = kt & 1, nxt = cur ^ 1;
    if (kt < 91) { STAGEB(kt + 1, nxt); STAGESRC(kt + 1, nxt); }

    const unsigned char* Bb = LB + cur * 16384;
    const unsigned char* Pb = LB + 32768 + cur * 4096;
    const unsigned char* Qb = LB + 40960 + cur * 1024;

#pragma unroll
    for (int kh = 0; kh < 2; ++kh) {        // two K=16 fragments per K=32 step
      int s16 = kh * 2 + lh;                // 16B k-slot within 64B B-row / slot32 for P2
      // P2[jj] : 8 f32 at k-slice, 16B-slot swizzled
      int sb = kh * 4 + lh * 2;
      fv4 p0 = *(const fv4*)(Pb + jj * 128 + ((sb    ) ^ (jj & 7)) * 16);
      fv4 p1 = *(const fv4*)(Pb + jj * 128 + ((sb + 1) ^ (jj & 7)) * 16);
      // Q broadcast rows (i = i0 + mw*2 + mf), linear layout
      fv4 qv[2][2];
#pragma unroll
      for (int mf = 0; mf < 2; ++mf) {
        const unsigned char* qp = Qb + (mw * 2 + mf) * 128 + s16 * 32;
        qv[mf][0] = *(const fv4*)(qp);
        qv[mf][1] = *(const fv4*)(qp + 16);
      }
      // B fragments: col = nf*32 + jj (within n-half), slot XOR-swizzled
      bf16x8 bF[4];
#pragma unroll
      for (int nf = 0; nf < 4; ++nf) {
        int row = nw * 128 + nf * 32 + jj;
        bF[nf] = *(const bf16x8*)(Bb + row * 64 + ((s16 ^ ((row >> 1) & 3))) * 16);
      }
      // A fragments: relu(Q[i_mf] + P2[jj]) -> bf16 (packed math)
      bf16x8 aF[2];
#pragma unroll
      for (int mf = 0; mf < 2; ++mf) {
        fv2 s00 = pk_add(lo2(qv[mf][0]), lo2(p0));
        fv2 s01 = pk_add(hi2(qv[mf][0]), hi2(p0));
        fv2 s10 = pk_add(lo2(qv[mf][1]), lo2(p1));
        fv2 s11 = pk_add(hi2(qv[mf][1]), hi2(p1));
        uiv4 u;
        u[0] = pk_relu2(cvt_pk_bf16(s00[0], s00[1]), z0);
        u[1] = pk_relu2(cvt_pk_bf16(s01[0], s01[1]), z0);
        u[2] = pk_relu2(cvt_pk_bf16(s10[0], s10[1]), z0);
        u[3] = pk_relu2(cvt_pk_bf16(s11[0], s11[1]), z0);
        aF[mf] = __builtin_bit_cast(bf16x8, u);
      }
#pragma unroll
      for (int nf = 0; nf < 4; ++nf)
#pragma unroll
        for (int mf = 0; mf < 2; ++mf)
          acc[mf][nf] = __builtin_amdgcn_mfma_f32_32x32x16_bf16(aF[mf], bF[nf], acc[mf][nf], 0, 0, 0);
    }
    __syncthreads();
  }

  // epilogue: h2 = relu(acc + b2); partial logits = h2 @ W3 chunk (128 n-cols
  // per wave); reduce over the 32 lanes of each half (xor 1..16 stays in-half);
  // cross-wave LDS reduce over n-halves; atomicAdd.
  float* red = (float*)LB;   // [4][704]
#pragma unroll
  for (int mf = 0; mf < 2; ++mf) {
#pragma unroll
    for (int rq = 0; rq < 4; ++rq) {
      float s[4][NA];
#pragma unroll
      for (int rr = 0; rr < 4; ++rr)
#pragma unroll
        for (int a = 0; a < NA; ++a) s[rr][a] = 0.f;
#pragma unroll
      for (int nf = 0; nf < 4; ++nf) {
        int nb = n0 + nw * 128 + nf * 32;
        if (nb < FEAT) {  // boundary multiple of 32 -> uniform per nf
          int n = nb + jj;
          float bv = b2[n];
          float w3r[NA];
#pragma unroll
          for (int a = 0; a < NA; ++a) w3r[a] = W3[n * NA + a];
#pragma unroll
          for (int rr = 0; rr < 4; ++rr) {
            float h = fmaxf(acc[mf][nf][rq * 4 + rr] + bv, 0.f);
#pragma unroll
            for (int a = 0; a < NA; ++a) s[rr][a] += h * w3r[a];
          }
        }
      }
#pragma unroll
      for (int off = 1; off < 32; off <<= 1)
#pragma unroll
        for (int rr = 0; rr < 4; ++rr)
#pragma unroll
          for (int a = 0; a < NA; ++a) s[rr][a] += __shfl_xor(s[rr][a], off, 64);
      if (jj < NA) {
        int a = jj;
#pragma unroll
        for (int rr = 0; rr < 4; ++rr) {
          int Lrow = mf * 32 + 8 * rq + rr + 4 * lh;   // wave-local row 0..63
          red[w * 704 + Lrow * NA + a] = s[rr][a];
        }
      }
    }
  }
  __syncthreads();
  for (int e = tid; e < 128 * NA; e += 256) {
    int row = e / NA, a = e - row * NA;
    int wr = row >> 6, rr = row & 63;
    float v = red[(wr * 2 + 0) * 704 + rr * NA + a] + red[(wr * 2 + 1) * 704 + rr * NA + a];
    atomicAdd(&Lout[(size_t)(m0 + row) * NA + a], v);
  }
}

// ---- symmetrize + b3 ----
__global__ void k_sym(const float* __restrict__ Lraw, const float* __restrict__ b3,
                      float* __restrict__ out) {
  int e = blockIdx.x * 256 + threadIdx.x;
  if (e >= MEDGE * NA) return;
  int m = e / NA, a = e - m * NA;
  int msw = (m & ~1023) | ((m & 31) << 5) | ((m >> 5) & 31);
  out[e] = 0.5f * (Lraw[e] + Lraw[(size_t)msw * NA + a]) + b3[a];
}

extern "C" void kernel_launch(void* const* d_in, const int* in_sizes, int n_in,
                              void* d_out, int out_size, void* d_ws, size_t ws_size,
                              hipStream_t stream) {
  const int*   idx      = (const int*)d_in[0];
  const int*   mlt      = (const int*)d_in[1];
  const float* z        = (const float*)d_in[2];
  const float* id_emb   = (const float*)d_in[3];
  const float* mult_emb = (const float*)d_in[4];
  const float* W1       = (const float*)d_in[5];
  const float* b1       = (const float*)d_in[6];
  const float* W2       = (const float*)d_in[7];
  const float* b2       = (const float*)d_in[8];
  const float* W3       = (const float*)d_in[9];
  const float* b3       = (const float*)d_in[10];
  float* out = (float*)d_out;

  uint8_t* ws = (uint8_t*)d_ws;
  size_t o = 0;
  auto alloc = [&](size_t bytes) { size_t r = o; o += (bytes + 255) & ~(size_t)255; return r; };
  size_t oW1T = alloc((size_t)HIDN * FEAT * 2);       // bf16 [2944][1472]
  size_t oW2T = alloc((size_t)FEATP * HIDN * 2);      // bf16 [1536][2944]
  size_t oXB  = alloc((size_t)NROWS * DNODE * 2);     // bf16 [2048][320]
  size_t oZA  = alloc((size_t)128 * 832 * 2);         // bf16 [128][832]
  size_t oAG  = alloc((size_t)NBG * DNODE * 4);       // f32  [64][320]
  size_t oP1  = alloc((size_t)NROWS * HIDN * 4);      // f32  [2048][2944]
  size_t oP2  = alloc((size_t)NROWS * HIDN * 4);
  size_t oQ   = alloc((size_t)NBG * HIDN * 4);
  size_t oLR  = alloc((size_t)MEDGE * NA * 4);        // single f32 slice
  if (ws_size < o) return;  // insufficient workspace (71.2 MB, known to fit)

  unsigned short* W1T = (unsigned short*)(ws + oW1T);
  unsigned short* W2T = (unsigned short*)(ws + oW2T);
  unsigned short* xb  = (unsigned short*)(ws + oXB);
  unsigned short* za  = (unsigned short*)(ws + oZA);
  float* agg = (float*)(ws + oAG);
  float* P1  = (float*)(ws + oP1);
  float* P2  = (float*)(ws + oP2);
  float* Qm  = (float*)(ws + oQ);
  float* LR  = (float*)(ws + oLR);

  k_transpose_bf16<<<dim3(FEAT / 64, HIDN / 64), 256, 0, stream>>>(W1, W1T, FEAT, HIDN, HIDN);
  k_transpose_bf16<<<dim3(HIDN / 64, FEATP / 64), 256, 0, stream>>>(W2, W2T, HIDN, FEAT, FEATP);
  k_embed<<<NROWS, 256, 0, stream>>>(idx, mlt, id_emb, mult_emb, xb);
  k_agg<<<NBG, 256, 0, stream>>>(xb, agg);
  k_za<<<128, 256, 0, stream>>>(z, agg, za);
  k_gemm1<<<16 * 23, 256, 0, stream>>>(xb, DNODE, NROWS, W1T, 0, 10, P1, nullptr);
  k_gemm1<<<16 * 23, 256, 0, stream>>>(xb, DNODE, NROWS, W1T, 320, 10, P2, nullptr);
  k_gemm1<<<1 * 23, 256, 0, stream>>>(za, 832, NBG, W1T, 640, 26, Qm, b1);
  k_pq<<<NROWS, 256, 0, stream>>>(P1, Qm);
  k_zero<<<(MEDGE * NA + 255) / 256, 256, 0, stream>>>(LR, MEDGE * NA);
  k_gemm2<<<512 * 6, 256, 0, stream>>>(P1, P2, W2T, b2, W3, LR);
  k_sym<<<(MEDGE * NA + 255) / 256, 256, 0, stream>>>(LR, b3, out);
}

// Round 16
// 1133.231 us; speedup vs baseline: 1.1415x; 1.1415x over previous
//
#include <hip/hip_runtime.h>
#include <stdint.h>

// ---- problem constants ----
#define NBG   64      // graphs
#define NPER  32      // nodes per graph
#define DNODE 320
#define FEAT  1472
#define HIDN  2944
#define FEATP 1536    // FEAT padded to x128 for layer-2 N
#define NA    11
#define NROWS 2048    // NBG*NPER
#define MEDGE 65536   // NBG*NPER*NPER

typedef __attribute__((ext_vector_type(8))) short    bf16x8;
typedef __attribute__((ext_vector_type(4))) float    fv4;
typedef __attribute__((ext_vector_type(2))) float    fv2;
typedef __attribute__((ext_vector_type(4))) unsigned uiv4;

__device__ __forceinline__ unsigned short f2bf(float f) {
  unsigned u = __builtin_bit_cast(unsigned, f);
  u += 0x7fffu + ((u >> 16) & 1u);
  return (unsigned short)(u >> 16);
}
__device__ __forceinline__ float bf2f(unsigned short h) {
  unsigned u = ((unsigned)h) << 16;
  return __builtin_bit_cast(float, u);
}
__device__ __forceinline__ unsigned cvt_pk_bf16(float lo, float hi) {
  unsigned r;
  asm("v_cvt_pk_bf16_f32 %0, %1, %2" : "=v"(r) : "v"(lo), "v"(hi));
  return r;
}
// packed f32 add (VOP3P) — one instr for two adds
__device__ __forceinline__ fv2 pk_add(fv2 a, fv2 b) {
  fv2 d;
  asm("v_pk_add_f32 %0, %1, %2" : "=v"(d) : "v"(a), "v"(b));
  return d;
}
// relu on 2 packed bf16: positive bf16 sorts as positive i16; negative -> 0.
__device__ __forceinline__ unsigned pk_relu2(unsigned x, unsigned z) {
  unsigned r;
  asm("v_pk_max_i16 %0, %1, %2" : "=v"(r) : "v"(x), "v"(z));
  return r;
}
__device__ __forceinline__ fv2 lo2(fv4 v) { return __builtin_shufflevector(v, v, 0, 1); }
__device__ __forceinline__ fv2 hi2(fv4 v) { return __builtin_shufflevector(v, v, 2, 3); }
// async global->LDS, 16B per lane; lds base wave-uniform (HW adds lane*16)
__device__ __forceinline__ void gload_lds16(const void* g, void* l) {
  __builtin_amdgcn_global_load_lds((const __attribute__((address_space(1))) void*)g,
                                   (__attribute__((address_space(3))) void*)l, 16, 0, 0);
}

// ---- transpose f32 [K][N] -> bf16 [Npad][K]; rows n>=N zero-filled ----
__global__ void k_transpose_bf16(const float* __restrict__ src, unsigned short* __restrict__ dst,
                                 int K, int N, int Npad) {
  __shared__ float tile[64][65];
  int k0 = blockIdx.x * 64, n0 = blockIdx.y * 64;
  int r = threadIdx.x >> 2, cb = (threadIdx.x & 3) * 16;
  const float* srow = src + (size_t)(k0 + r) * N + n0 + cb;
#pragma unroll
  for (int c = 0; c < 16; ++c) {
    int n = n0 + cb + c;
    tile[r][cb + c] = (n < N) ? srow[c] : 0.f;
  }
  __syncthreads();
  unsigned short* drow = dst + (size_t)(n0 + r) * K + k0 + cb;
#pragma unroll
  for (int c = 0; c < 16; ++c) drow[c] = f2bf(tile[cb + c][r]);
}

// ---- embeddings -> xb bf16 [2048][320] ----
__global__ void k_embed(const int* __restrict__ idx, const int* __restrict__ mlt,
                        const float* __restrict__ id_emb, const float* __restrict__ mult_emb,
                        unsigned short* __restrict__ xb) {
  int t = blockIdx.x, c = threadIdx.x;
  int iv = idx[t], mv = mlt[t];
  xb[t * DNODE + c] = f2bf(id_emb[iv * 256 + c]);
  if (c < 64) xb[t * DNODE + 256 + c] = f2bf(mult_emb[mv * 64 + c]);
}

// ---- agg f32 [64][320] = mean over 32 nodes ----
__global__ void k_agg(const unsigned short* __restrict__ xb, float* __restrict__ agg) {
  int b = blockIdx.x;
  for (int d = threadIdx.x; d < DNODE; d += 256) {
    float s = 0.f;
    for (int i = 0; i < NPER; ++i) s += bf2f(xb[(b * NPER + i) * DNODE + d]);
    agg[b * DNODE + d] = s * (1.f / 32.f);
  }
}

// ---- za bf16 [128][832] = [z | agg], rows 64..127 zero ----
__global__ void k_za(const float* __restrict__ z, const float* __restrict__ agg,
                     unsigned short* __restrict__ za) {
  int b = blockIdx.x;
  for (int c = threadIdx.x; c < 832; c += 256) {
    unsigned short v = 0;
    if (b < NBG) v = (c < 512) ? f2bf(z[b * 512 + c]) : f2bf(agg[b * DNODE + (c - 512)]);
    za[b * 832 + c] = v;
  }
}

// ---- layer-1 GEMM: C[M][2944] (f32) = A(bf16,[M][sA] slice) @ W1T(bf16 [2944][1472])^T ----
__global__ void k_gemm1(const unsigned short* __restrict__ A, int sA, int Mrows,
                        const unsigned short* __restrict__ W1T, int kOff, int Ksteps,
                        float* __restrict__ C, const float* __restrict__ bias) {
  __shared__ alignas(16) unsigned short Als[128 * 32];
  __shared__ alignas(16) unsigned short Bls[128 * 32];
  int bx = blockIdx.x;
  int mt = bx / 23, nc = bx - mt * 23;
  int m0 = mt * 128, n0 = nc * 128;
  int tid = threadIdx.x, lane = tid & 63, w = tid >> 6;

  fv4 acc[4][4] = {};
  for (int kt = 0; kt < Ksteps; ++kt) {
    int k0 = kt * 32;
    __syncthreads();
#pragma unroll
    for (int q = 0; q < 2; ++q) {
      int seg = w * 2 + q;
      int row = seg * 16 + (lane >> 2);
      int col = (lane & 3) * 8;
      gload_lds16(A + (size_t)(m0 + row) * sA + k0 + col, &Als[seg * 512]);
      gload_lds16(W1T + (size_t)(n0 + row) * FEAT + kOff + k0 + col, &Bls[seg * 512]);
    }
    __syncthreads();
    bf16x8 aF[4], bF[4];
#pragma unroll
    for (int mf = 0; mf < 4; ++mf)
      aF[mf] = *(const bf16x8*)&Als[((w >> 1) * 64 + mf * 16 + (lane & 15)) * 32 + (lane >> 4) * 8];
#pragma unroll
    for (int nf = 0; nf < 4; ++nf)
      bF[nf] = *(const bf16x8*)&Bls[((w & 1) * 64 + nf * 16 + (lane & 15)) * 32 + (lane >> 4) * 8];
#pragma unroll
    for (int mf = 0; mf < 4; ++mf)
#pragma unroll
      for (int nf = 0; nf < 4; ++nf)
        acc[mf][nf] = __builtin_amdgcn_mfma_f32_16x16x32_bf16(aF[mf], bF[nf], acc[mf][nf], 0, 0, 0);
  }
  int mq = (w >> 1) * 64, nq = (w & 1) * 64;
#pragma unroll
  for (int mf = 0; mf < 4; ++mf)
#pragma unroll
    for (int nf = 0; nf < 4; ++nf) {
      int n = n0 + nq + nf * 16 + (lane & 15);
      float bv = bias ? bias[n] : 0.f;
#pragma unroll
      for (int r = 0; r < 4; ++r) {
        int m = m0 + mq + mf * 16 + (lane >> 4) * 4 + r;
        if (m < Mrows) C[(size_t)m * HIDN + n] = acc[mf][nf][r] + bv;
      }
    }
}

// ---- PQ1 = P1 + Q[b] (in place on P1; Q already includes b1) ----
__global__ void k_pq(float* __restrict__ P1, const float* __restrict__ Q) {
  int r = blockIdx.x;
  const float* q = Q + (size_t)(r >> 5) * HIDN;
  float* p = P1 + (size_t)r * HIDN;
  for (int n = threadIdx.x; n < HIDN; n += 256) p[n] += q[n];
}

__global__ void k_zero(float* __restrict__ p, int n) {
  int i = blockIdx.x * 256 + threadIdx.x;
  if (i < n) p[i] = 0.f;
}

// ---- layer-2 GEMM fused with layer-3 partial, N=256 per block (champion) ----
// Session champion (R11, 1134 us total): 3072 blocks, 2-barrier double-
// buffered staging, on-the-fly A-construct with packed math, 32 MFMA per
// wave-step, atomic epilogue, NC-MAJOR XCD dispatch order (each XCD's
// time-sequential blocks share one 1.5 MB W2T panel -> L2-resident; FETCH
// 497->246 MB). Structure verified to be at its latency/issue-economy floor:
// schedule variants (R1/R7/R10), traffic cuts (R6/R8), occupancy (R12-14),
// and MFMA shape (R15) are all null or negative around this point.
// LDS: B[2][16384] @0 | P2s[2][4096] @32768 | PQ1s[2][1024] @40960 = 43008
__global__ __launch_bounds__(256, 2)
void k_gemm2(const float* __restrict__ PQ1, const float* __restrict__ P2,
             const unsigned short* __restrict__ W2T,
             const float* __restrict__ b2, const float* __restrict__ W3,
             float* __restrict__ Lout) {
  __shared__ alignas(16) unsigned char LB[43008];
  int raw = blockIdx.x;
  int g = (raw & 7) * 384 + (raw >> 3);   // bijective: 3072 = 8 * 384
  int nc2 = g / 512;                      // panel index: constant per XCD span
  int mt  = g - nc2 * 512;                // sequential m-tiles within a panel
  int m0 = mt * 128, n0 = nc2 * 256;
  int tid = threadIdx.x, lane = tid & 63, w = tid >> 6;
  int bG = m0 >> 10;
  int i0 = (m0 >> 5) & 31;
  int ks = lane >> 4;
  int r  = lane & 15;

  const int swcolB = ((lane & 3) ^ ((lane >> 3) & 3)) * 8;
  const int swcolP = (((lane >> 1) & 3) ^ ((lane >> 3) & 3)) * 8 + (lane & 1) * 4;

  auto STAGEB = [&](int kt, int buf) {
#pragma unroll
    for (int q = 0; q < 4; ++q) {
      int seg = w * 4 + q;
      int row = seg * 16 + (lane >> 2);
      gload_lds16(W2T + (size_t)(n0 + row) * HIDN + kt * 32 + swcolB,
                  LB + buf * 16384 + seg * 1024);
    }
  };
  auto STAGESRC = [&](int kt, int buf) {
    gload_lds16(P2 + (size_t)(bG * NPER + 8 * w + (lane >> 3)) * HIDN + kt * 32 + swcolP,
                LB + 32768 + buf * 4096 + w * 1024);
    if (w == 0)
      gload_lds16(PQ1 + (size_t)(bG * NPER + i0 + (lane >> 3)) * HIDN + kt * 32 + (lane & 7) * 4,
                  LB + 40960 + buf * 1024);
  };

  fv4 acc[4][8] = {};
  unsigned z0 = 0;
  asm volatile("" : "+v"(z0));   // keep zero in a VGPR for pk_max

  STAGEB(0, 0);
  STAGESRC(0, 0);
  __syncthreads();

  int il0 = (w >> 1) * 2;
  for (int kt = 0; kt < 92; ++kt) {
    int cur = kt & 1, nxt = cur ^ 1;
    if (kt < 91) { STAGEB(kt + 1, nxt); STAGESRC(kt + 1, nxt); }

    const unsigned char* Bb = LB + cur * 16384;
    const unsigned char* Pb = LB + 32768 + cur * 4096;
    const unsigned char* Qb = LB + 40960 + cur * 1024;

    int psw = (ks ^ (r & 3)) * 32;
    fv4 q0[2], q1[2], p0[2], p1[2];
#pragma unroll
    for (int h = 0; h < 2; ++h) {
      q0[h] = *(const fv4*)(Qb + il0 * 128 + ks * 32 + h * 16);        // broadcast
      q1[h] = *(const fv4*)(Qb + (il0 + 1) * 128 + ks * 32 + h * 16);  // broadcast
      p0[h] = *(const fv4*)(Pb + r * 128 + psw + h * 16);
      p1[h] = *(const fv4*)(Pb + (16 + r) * 128 + psw + h * 16);
    }
    bf16x8 bF[8];
#pragma unroll
    for (int nf = 0; nf < 8; ++nf) {
      int brow = (w & 1) * 128 + nf * 16 + r;
      int slot = ks ^ ((brow >> 1) & 3);
      bF[nf] = *(const bf16x8*)(Bb + brow * 64 + slot * 16);
    }

    // construct A fragments: bf16(PQ1[i]+P2[j]) then packed relu
    bf16x8 aF[4];
#pragma unroll
    for (int mf = 0; mf < 4; ++mf) {
      fv4 qa0 = (mf & 2) ? q1[0] : q0[0];
      fv4 qa1 = (mf & 2) ? q1[1] : q0[1];
      fv4 pa0 = (mf & 1) ? p1[0] : p0[0];
      fv4 pa1 = (mf & 1) ? p1[1] : p0[1];
      fv2 s00 = pk_add(lo2(qa0), lo2(pa0));
      fv2 s01 = pk_add(hi2(qa0), hi2(pa0));
      fv2 s10 = pk_add(lo2(qa1), lo2(pa1));
      fv2 s11 = pk_add(hi2(qa1), hi2(pa1));
      uiv4 u;
      u[0] = pk_relu2(cvt_pk_bf16(s00[0], s00[1]), z0);
      u[1] = pk_relu2(cvt_pk_bf16(s01[0], s01[1]), z0);
      u[2] = pk_relu2(cvt_pk_bf16(s10[0], s10[1]), z0);
      u[3] = pk_relu2(cvt_pk_bf16(s11[0], s11[1]), z0);
      aF[mf] = __builtin_bit_cast(bf16x8, u);
    }

#pragma unroll
    for (int nf = 0; nf < 8; ++nf)
#pragma unroll
      for (int mf = 0; mf < 4; ++mf)
        acc[mf][nf] = __builtin_amdgcn_mfma_f32_16x16x32_bf16(aF[mf], bF[nf], acc[mf][nf], 0, 0, 0);
    __syncthreads();
  }

  // epilogue: h2 = relu(acc + b2); partial logits = h2 @ W3 chunk (128 n-cols
  // per wave); wave shfl reduce; cross-wave LDS reduce; atomicAdd.
  float* red = (float*)LB;
  int nq = (w & 1) * 128;
#pragma unroll
  for (int mf = 0; mf < 4; ++mf) {
    float s[4][NA];
#pragma unroll
    for (int rr = 0; rr < 4; ++rr)
#pragma unroll
      for (int a = 0; a < NA; ++a) s[rr][a] = 0.f;
#pragma unroll
    for (int nf = 0; nf < 8; ++nf) {
      int n = n0 + nq + nf * 16 + r;
      if (n < FEAT) {  // boundary multiple of 16 -> uniform per nf
        float bv = b2[n];
        float w3r[NA];
#pragma unroll
        for (int a = 0; a < NA; ++a) w3r[a] = W3[n * NA + a];
#pragma unroll
        for (int rr = 0; rr < 4; ++rr) {
          float h = fmaxf(acc[mf][nf][rr] + bv, 0.f);
#pragma unroll
          for (int a = 0; a < NA; ++a) s[rr][a] += h * w3r[a];
        }
      }
    }
#pragma unroll
    for (int off = 1; off < 16; off <<= 1)
#pragma unroll
      for (int rr = 0; rr < 4; ++rr)
#pragma unroll
        for (int a = 0; a < NA; ++a) s[rr][a] += __shfl_xor(s[rr][a], off, 64);
    int a = r;
    if (a < NA) {
#pragma unroll
      for (int rr = 0; rr < 4; ++rr)
        red[w * 704 + (mf * 16 + ks * 4 + rr) * NA + a] = s[rr][a];
    }
  }
  __syncthreads();
  for (int e = tid; e < 128 * NA; e += 256) {
    int row = e / NA, a = e - row * NA;
    int wr = row >> 6, rr = row & 63;
    float v = red[(wr * 2 + 0) * 704 + rr * NA + a] + red[(wr * 2 + 1) * 704 + rr * NA + a];
    atomicAdd(&Lout[(size_t)(m0 + row) * NA + a], v);
  }
}

// ---- symmetrize + b3 ----
__global__ void k_sym(const float* __restrict__ Lraw, const float* __restrict__ b3,
                      float* __restrict__ out) {
  int e = blockIdx.x * 256 + threadIdx.x;
  if (e >= MEDGE * NA) return;
  int m = e / NA, a = e - m * NA;
  int msw = (m & ~1023) | ((m & 31) << 5) | ((m >> 5) & 31);
  out[e] = 0.5f * (Lraw[e] + Lraw[(size_t)msw * NA + a]) + b3[a];
}

extern "C" void kernel_launch(void* const* d_in, const int* in_sizes, int n_in,
                              void* d_out, int out_size, void* d_ws, size_t ws_size,
                              hipStream_t stream) {
  const int*   idx      = (const int*)d_in[0];
  const int*   mlt      = (const int*)d_in[1];
  const float* z        = (const float*)d_in[2];
  const float* id_emb   = (const float*)d_in[3];
  const float* mult_emb = (const float*)d_in[4];
  const float* W1       = (const float*)d_in[5];
  const float* b1       = (const float*)d_in[6];
  const float* W2       = (const float*)d_in[7];
  const float* b2       = (const float*)d_in[8];
  const float* W3       = (const float*)d_in[9];
  const float* b3       = (const float*)d_in[10];
  float* out = (float*)d_out;

  uint8_t* ws = (uint8_t*)d_ws;
  size_t o = 0;
  auto alloc = [&](size_t bytes) { size_t r = o; o += (bytes + 255) & ~(size_t)255; return r; };
  size_t oW1T = alloc((size_t)HIDN * FEAT * 2);       // bf16 [2944][1472]
  size_t oW2T = alloc((size_t)FEATP * HIDN * 2);      // bf16 [1536][2944]
  size_t oXB  = alloc((size_t)NROWS * DNODE * 2);     // bf16 [2048][320]
  size_t oZA  = alloc((size_t)128 * 832 * 2);         // bf16 [128][832]
  size_t oAG  = alloc((size_t)NBG * DNODE * 4);       // f32  [64][320]
  size_t oP1  = alloc((size_t)NROWS * HIDN * 4);      // f32  [2048][2944]
  size_t oP2  = alloc((size_t)NROWS * HIDN * 4);
  size_t oQ   = alloc((size_t)NBG * HIDN * 4);
  size_t oLR  = alloc((size_t)MEDGE * NA * 4);        // single f32 slice
  if (ws_size < o) return;  // insufficient workspace (71.2 MB, known to fit)

  unsigned short* W1T = (unsigned short*)(ws + oW1T);
  unsigned short* W2T = (unsigned short*)(ws + oW2T);
  unsigned short* xb  = (unsigned short*)(ws + oXB);
  unsigned short* za  = (unsigned short*)(ws + oZA);
  float* agg = (float*)(ws + oAG);
  float* P1  = (float*)(ws + oP1);
  float* P2  = (float*)(ws + oP2);
  float* Qm  = (float*)(ws + oQ);
  float* LR  = (float*)(ws + oLR);

  k_transpose_bf16<<<dim3(FEAT / 64, HIDN / 64), 256, 0, stream>>>(W1, W1T, FEAT, HIDN, HIDN);
  k_transpose_bf16<<<dim3(HIDN / 64, FEATP / 64), 256, 0, stream>>>(W2, W2T, HIDN, FEAT, FEATP);
  k_embed<<<NROWS, 256, 0, stream>>>(idx, mlt, id_emb, mult_emb, xb);
  k_agg<<<NBG, 256, 0, stream>>>(xb, agg);
  k_za<<<128, 256, 0, stream>>>(z, agg, za);
  k_gemm1<<<16 * 23, 256, 0, stream>>>(xb, DNODE, NROWS, W1T, 0, 10, P1, nullptr);
  k_gemm1<<<16 * 23, 256, 0, stream>>>(xb, DNODE, NROWS, W1T, 320, 10, P2, nullptr);
  k_gemm1<<<1 * 23, 256, 0, stream>>>(za, 832, NBG, W1T, 640, 26, Qm, b1);
  k_pq<<<NROWS, 256, 0, stream>>>(P1, Qm);
  k_zero<<<(MEDGE * NA + 255) / 256, 256, 0, stream>>>(LR, MEDGE * NA);
  k_gemm2<<<512 * 6, 256, 0, stream>>>(P1, P2, W2T, b2, W3, LR);
  k_sym<<<(MEDGE * NA + 255) / 256, 256, 0, stream>>>(LR, b3, out);
}